// Round 2
// baseline (399.447 us; speedup 1.0000x reference)
//
#include <hip/hip_runtime.h>
#include <hip/hip_bf16.h>

// Problem constants (from setup_inputs): b=4, h=128, w=512, c=128, num_splits=8
#define BH      512   // b*h
#define W_ROWS  512   // w
#define C_DIM   128   // c
#define NSPLIT  8
#define WIN     64
#define SHIFT   32    // win/2

typedef __attribute__((ext_vector_type(8))) short  short8;
typedef __attribute__((ext_vector_type(4))) float  floatx4;

__device__ __forceinline__ ushort f2bf(float x) {
    union { float f; unsigned u; } c; c.f = x;
    unsigned u = c.u;
    return (ushort)((u + 0x7FFFu + ((u >> 16) & 1u)) >> 16);  // RNE
}

// One block per (bh, split) window: 64 queries x 64 keys x 128 channels.
// 4 waves; wave wv owns query rows [16*wv, 16*wv+16).
__global__ __launch_bounds__(256)
void swin_attn_kernel(const float* __restrict__ qg,
                      const float* __restrict__ kg,
                      const float* __restrict__ vg,
                      const float* __restrict__ mg,
                      float* __restrict__ og)
{
    // +8 element padding keeps b128 fragment reads at <=2-way bank aliasing (free)
    __shared__ __align__(16) ushort sK [64][136];   // K row-major bf16
    __shared__ __align__(16) ushort sVt[128][72];   // V transposed bf16: [channel][key]
    __shared__ __align__(16) ushort sP [64][72];    // softmax probs bf16

    const int tid  = threadIdx.x;
    const int bh   = blockIdx.x >> 3;
    const int s    = blockIdx.x & 7;
    const int wv   = tid >> 6;     // wave 0..3
    const int lane = tid & 63;
    const int l16  = lane & 15;
    const int quad = lane >> 4;

    const size_t base = (size_t)bh * (W_ROWS * C_DIM);

    // ---- stage K (row-major) and V (transposed) into LDS as bf16 ----
    for (int i = 0; i < 8; ++i) {
        int idx = i * 256 + tid;              // 0..2047 float4-chunks
        int row = idx >> 5;                   // key row 0..63
        int c0  = (idx & 31) << 2;            // channel base, step 4
        int rg  = (s * WIN + row + SHIFT) & (W_ROWS - 1);   // rolled source row
        size_t goff = base + (size_t)rg * C_DIM + c0;
        float4 kv = *(const float4*)(kg + goff);
        ushort4 kb;
        kb.x = f2bf(kv.x); kb.y = f2bf(kv.y); kb.z = f2bf(kv.z); kb.w = f2bf(kv.w);
        *(ushort4*)&sK[row][c0] = kb;
        float4 vv = *(const float4*)(vg + goff);
        sVt[c0 + 0][row] = f2bf(vv.x);
        sVt[c0 + 1][row] = f2bf(vv.y);
        sVt[c0 + 2][row] = f2bf(vv.z);
        sVt[c0 + 3][row] = f2bf(vv.w);
    }
    __syncthreads();

    // ---- QK^T: scores[q][key], per-wave 16x64 strip ----
    floatx4 acc[4];
    const floatx4 fz = {0.f, 0.f, 0.f, 0.f};
    for (int t = 0; t < 4; ++t) acc[t] = fz;

    const int qrow = wv * 16 + l16;                                // A-frag row (m = lane&15)
    const int rgq  = (s * WIN + qrow + SHIFT) & (W_ROWS - 1);
    const float* qp = qg + base + (size_t)rgq * C_DIM + quad * 8;  // k = quad*8 + j

    for (int kk = 0; kk < 4; ++kk) {          // K-dim steps of 32 channels
        float4 a0 = *(const float4*)(qp + kk * 32);
        float4 a1 = *(const float4*)(qp + kk * 32 + 4);
        short8 af;
        af[0] = (short)f2bf(a0.x); af[1] = (short)f2bf(a0.y);
        af[2] = (short)f2bf(a0.z); af[3] = (short)f2bf(a0.w);
        af[4] = (short)f2bf(a1.x); af[5] = (short)f2bf(a1.y);
        af[6] = (short)f2bf(a1.z); af[7] = (short)f2bf(a1.w);
        const int ch0 = kk * 32 + quad * 8;
        for (int t = 0; t < 4; ++t) {         // key tiles of 16
            short8 bf = *(const short8*)&sK[t * 16 + l16][ch0];
            acc[t] = __builtin_amdgcn_mfma_f32_16x16x32_bf16(af, bf, acc[t], 0, 0, 0);
        }
    }

    // ---- scale + mask + softmax (fp32), write P (bf16) to LDS ----
    // C/D layout: col = lane&15 (+16*t), row = quad*4 + r (+16*wv)
    const float* mrow = mg + s * (WIN * WIN);
    float pr[4][4];                            // [t][r]
    for (int r = 0; r < 4; ++r) {
        const int qw = wv * 16 + quad * 4 + r; // window-local query row
        float mx = -3.0e38f;
        for (int t = 0; t < 4; ++t) {
            float val = acc[t][r] * 0.08838834764831845f      // 1/sqrt(128)
                      + mrow[qw * WIN + t * 16 + l16];
            pr[t][r] = val;
            mx = fmaxf(mx, val);
        }
        mx = fmaxf(mx, __shfl_xor(mx, 1));
        mx = fmaxf(mx, __shfl_xor(mx, 2));
        mx = fmaxf(mx, __shfl_xor(mx, 4));
        mx = fmaxf(mx, __shfl_xor(mx, 8));
        float sum = 0.f;
        for (int t = 0; t < 4; ++t) {
            float e = __expf(pr[t][r] - mx);
            pr[t][r] = e;
            sum += e;
        }
        sum += __shfl_xor(sum, 1);
        sum += __shfl_xor(sum, 2);
        sum += __shfl_xor(sum, 4);
        sum += __shfl_xor(sum, 8);
        float rs = 1.0f / sum;
        for (int t = 0; t < 4; ++t)
            sP[qw][t * 16 + l16] = f2bf(pr[t][r] * rs);
    }
    __syncthreads();

    // ---- PV: out[q][ch] = sum_key P[q][key] * V[key][ch] ----
    floatx4 o[8];
    for (int t = 0; t < 8; ++t) o[t] = fz;
    for (int kk = 0; kk < 2; ++kk) {          // key steps of 32
        short8 pf = *(const short8*)&sP[wv * 16 + l16][kk * 32 + quad * 8];
        for (int t = 0; t < 8; ++t) {         // channel tiles of 16
            short8 vf = *(const short8*)&sVt[t * 16 + l16][kk * 32 + quad * 8];
            o[t] = __builtin_amdgcn_mfma_f32_16x16x32_bf16(pf, vf, o[t], 0, 0, 0);
        }
    }

    // ---- epilogue: fp32 store with inverse roll ----
    for (int r = 0; r < 4; ++r) {
        const int qw = wv * 16 + quad * 4 + r;
        const int rg = (s * WIN + qw + SHIFT) & (W_ROWS - 1);
        float* op = og + base + (size_t)rg * C_DIM + l16;
        for (int t = 0; t < 8; ++t)
            op[t * 16] = o[t][r];
    }
}

extern "C" void kernel_launch(void* const* d_in, const int* in_sizes, int n_in,
                              void* d_out, int out_size, void* d_ws, size_t ws_size,
                              hipStream_t stream) {
    const float* q = (const float*)d_in[0];
    const float* k = (const float*)d_in[1];
    const float* v = (const float*)d_in[2];
    const float* m = (const float*)d_in[3];
    float* out = (float*)d_out;
    dim3 grid(BH * NSPLIT), block(256);
    hipLaunchKernelGGL(swin_attn_kernel, grid, block, 0, stream, q, k, v, m, out);
}